// Round 13
// baseline (117.315 us; speedup 1.0000x reference)
//
#include <hip/hip_runtime.h>
#include <hip/hip_bf16.h>

#define B_ 8
#define N_ 2048
#define D_ 512
#define DK_ 64

typedef float f32x4 __attribute__((ext_vector_type(4)));
typedef short bf16x8 __attribute__((ext_vector_type(8)));
typedef short bf16x4 __attribute__((ext_vector_type(4)));
typedef unsigned int uint2v __attribute__((ext_vector_type(2)));
typedef unsigned long long u64x2 __attribute__((ext_vector_type(2)));
typedef unsigned short u16;

__device__ __forceinline__ u16 f2bf(float f) {
  union { float f; unsigned u; } v; v.f = f;
  unsigned r = v.u + 0x7FFFu + ((v.u >> 16) & 1u);  // RNE, inputs finite
  return (u16)(r >> 16);
}

#define MFMA32(a, b, cacc) __builtin_amdgcn_mfma_f32_16x16x32_bf16((a), (b), (cacc), 0, 0, 0)
// 16x16x16 bf16 (K=16): A/B = 4 bf16 per lane (k = (lane>>4)*4 + i)
#define MFMA16(a, b, cacc) __builtin_amdgcn_mfma_f32_16x16x16bf16_1k((a), (b), (cacc), 0, 0, 0)

// pack two f32 -> 2 bf16 in one dword (gfx950 VOP3, no builtin; T12 recipe)
__device__ __forceinline__ unsigned cvt_pk_bf16(float lo, float hi) {
  unsigned r;
  asm("v_cvt_pk_bf16_f32 %0, %1, %2" : "=v"(r) : "v"(lo), "v"(hi));
  return r;
}

// ===========================================================================
// Fragment layouts:
//  Qf/Kf (unchanged): elem((b*128 + slab)*2 + ks)*512 + lane*8 + i
//         holds M[slab*16 + (lane&15)][ks*32 + (lane>>4)*8 + i]
//         (serves as A- OR B-operand of 16x16x32: row/col = lane&15, k = dk)
//  Vf (k=16 PV frag pairs): elem((b*32 + dt)*64 + j)*512 + lane*8 + h*4 + i
//         holds X[j*32 + h*16 + (lane>>4)*4 + i][dt*16 + (lane&15)]
//         = B-operand pair (kv-halves h=0,1) for mfma 16x16x16, one b128/lane
// ===========================================================================

// ---------------------------------------------------------------------------
// Kernel 1: X f32 -> Vf bf16 (16-kv PV frag pairs).
// grid 2048 = b(8) x nt(32) x dt8(8); 64x64 tile via LDS transpose.
// ---------------------------------------------------------------------------
__global__ __launch_bounds__(256) void vt_kernel(const float* __restrict__ X,
                                                 u16* __restrict__ Vf) {
  int bid = blockIdx.x;
  int dt8 = bid & 7, nt = (bid >> 3) & 31, b = bid >> 8;
  int n0 = nt * 64, d0 = dt8 * 64;
  __shared__ u16 T[64 * 72];  // T[d_local][n_local]
  int t = threadIdx.x;
  const float* Xb = X + ((size_t)b * N_ + n0) * D_ + d0;
#pragma unroll
  for (int p = 0; p < 4; ++p) {
    int r = p * 16 + (t >> 4);      // n_local
    int c4 = (t & 15) * 4;          // d_local base
    f32x4 v = *reinterpret_cast<const f32x4*>(Xb + (size_t)r * D_ + c4);
#pragma unroll
    for (int j = 0; j < 4; ++j) T[(c4 + j) * 72 + r] = f2bf(v[j]);
  }
  __syncthreads();
  int w = t >> 6, l = t & 63, g = l >> 4, c = l & 15;
  // wave w -> dt = dt8*4 + w; two 32-kv windows jl=0,1 in this 64-n tile
#pragma unroll
  for (int jl = 0; jl < 2; ++jl) {
    u64x2 tmp;
    tmp[0] = *reinterpret_cast<const unsigned long long*>(
        &T[(w * 16 + c) * 72 + jl * 32 + 4 * g]);
    tmp[1] = *reinterpret_cast<const unsigned long long*>(
        &T[(w * 16 + c) * 72 + jl * 32 + 16 + 4 * g]);
    bf16x8 v = __builtin_bit_cast(bf16x8, tmp);
    *reinterpret_cast<bf16x8*>(
        Vf + (((size_t)(b * 32 + dt8 * 4 + w) * 64) + nt * 2 + jl) * 512 + l * 8) = v;
  }
}

// ---------------------------------------------------------------------------
// Kernel 2 (validated, unchanged): Qf = (h@WQ + bQ)/8, Kf = X@WK + bK.
// ---------------------------------------------------------------------------
__global__ __launch_bounds__(256) void proj_kernel(
    const float* __restrict__ h, const float* __restrict__ X,
    const float* __restrict__ WQ, const float* __restrict__ bQ,
    const float* __restrict__ WK, const float* __restrict__ bK,
    u16* __restrict__ Qf, u16* __restrict__ Kf) {
  int bid = blockIdx.x;
  int b = bid & 7, nt = bid >> 3;
  int n0 = nt * 64;
  int t = threadIdx.x, w = t >> 6, l = t & 63, g = l >> 4, c = l & 15;
  int arow = n0 + w * 16 + c;
  const float* hrow = h + ((size_t)b * N_ + arow) * D_;
  const float* Xrow = X + ((size_t)b * N_ + arow) * D_;
  f32x4 accq[4], acck[4];
#pragma unroll
  for (int cf = 0; cf < 4; ++cf) {
    accq[cf] = (f32x4){0.f, 0.f, 0.f, 0.f};
    acck[cf] = (f32x4){0.f, 0.f, 0.f, 0.f};
  }
  for (int k0 = 0; k0 < D_; k0 += 32) {
    bf16x8 ah, ax;
    {
      f32x4 h0 = *reinterpret_cast<const f32x4*>(hrow + k0 + 8 * g);
      f32x4 h1 = *reinterpret_cast<const f32x4*>(hrow + k0 + 8 * g + 4);
      f32x4 x0 = *reinterpret_cast<const f32x4*>(Xrow + k0 + 8 * g);
      f32x4 x1 = *reinterpret_cast<const f32x4*>(Xrow + k0 + 8 * g + 4);
#pragma unroll
      for (int i = 0; i < 4; ++i) {
        ah[i] = (short)f2bf(h0[i]); ah[i + 4] = (short)f2bf(h1[i]);
        ax[i] = (short)f2bf(x0[i]); ax[i + 4] = (short)f2bf(x1[i]);
      }
    }
#pragma unroll
    for (int cf = 0; cf < 4; ++cf) {
      bf16x8 bq, bk;
#pragma unroll
      for (int i = 0; i < 8; ++i) {
        int kk = k0 + 8 * g + i;
        bq[i] = (short)f2bf(WQ[(size_t)kk * DK_ + cf * 16 + c]);
        bk[i] = (short)f2bf(WK[(size_t)kk * DK_ + cf * 16 + c]);
      }
      accq[cf] = MFMA32(ah, bq, accq[cf]);
      acck[cf] = MFMA32(ax, bk, acck[cf]);
    }
  }
#pragma unroll
  for (int cf = 0; cf < 4; ++cf) {
    float vq = bQ[cf * 16 + c], vk = bK[cf * 16 + c];
    int ks = cf >> 1;
    int g2 = ((cf & 1) * 16 + c) >> 3;
    int i2 = c & 7;
#pragma unroll
    for (int r = 0; r < 4; ++r) {
      size_t e = ((size_t)(b * 128 + nt * 4 + w) * 2 + ks) * 512 +
                 (g2 * 16 + 4 * g + r) * 8 + i2;
      Qf[e] = f2bf((accq[cf][r] + vq) * 0.125f);
      Kf[e] = f2bf(acck[cf][r] + vk);
    }
  }
}

// ---------------------------------------------------------------------------
// attn: BARRIER-FREE register-softmax. 256 blocks x 512 threads (8 waves).
// Each wave: all 64q x its 64d slice, fully independent (no LDS/barrier in
// loop). S^T = mfma(A=K, B=Q) puts P in EXACTLY the A-frag layout of
// mfma_16x16x16 PV (k=16): lane(c,g) S^T[kv=4g+r][q=c] -> exp -> cvt_pk ->
// PV A-frag [row=q=c][k=kv=4g+i]. V = B-frag [k=kv=4g+i][col=d=c] (Vf).
// Cost: S & exp redundant x8 waves, K through L1 x8 (L1 ~64KB/CU/window =
// the predicted bound); buys zero phase-locking (R6-R11 diagnosis).
// ---------------------------------------------------------------------------
__global__ __launch_bounds__(512, 2) void attn_kernel(
    const u16* __restrict__ Qf, const u16* __restrict__ Kf,
    const u16* __restrict__ Vf, float* __restrict__ out) {
  int bid = blockIdx.x;
  int b = bid & 7, qt = bid >> 3;
  int q0 = qt * 64;
  int t = threadIdx.x, w = t >> 6, l = t & 63, g = l >> 4, c = l & 15;

  __shared__ float Lsh[8][64];

  // Q B-frags, resident: aq[slab][ks]
  bf16x8 aq[4][2];
#pragma unroll
  for (int sl = 0; sl < 4; ++sl)
#pragma unroll
    for (int ks = 0; ks < 2; ++ks)
      aq[sl][ks] = *reinterpret_cast<const bf16x8*>(
          Qf + ((size_t)(b * 128 + qt * 4 + sl) * 2 + ks) * 512 + l * 8);

  f32x4 o[4][4];
#pragma unroll
  for (int sl = 0; sl < 4; ++sl)
#pragma unroll
    for (int df = 0; df < 4; ++df) o[sl][df] = (f32x4){0.f, 0.f, 0.f, 0.f};
  float lp[4] = {0.f, 0.f, 0.f, 0.f};

  // K frag (window j, kvh, ks): Kbase + ((j*2+kvh)*2+ks)*512
  const u16* Kbase = Kf + ((size_t)b * 256) * 512 + l * 8;
  // V frag-pair (df, window j): Vbase + (df*64 + j)*512  (b128 = kvh 0|1)
  const u16* Vbase = Vf + ((size_t)(b * 32 + w * 4) * 64) * 512 + l * 8;

  bf16x8 kA[4], kB[4], vA[4], vB[4];

#define LOADW(kT, vT, j)                                                      \
  do {                                                                        \
    _Pragma("unroll") for (int kv2 = 0; kv2 < 4; ++kv2)                       \
        kT[kv2] = *reinterpret_cast<const bf16x8*>(                           \
            Kbase + (size_t)(((j) * 2 + (kv2 >> 1)) * 2 + (kv2 & 1)) * 512);  \
    _Pragma("unroll") for (int df = 0; df < 4; ++df)                          \
        vT[df] = *reinterpret_cast<const bf16x8*>(                            \
            Vbase + (size_t)(df * 64 + (j)) * 512);                           \
  } while (0)

  LOADW(kA, vA, 0);

  auto body = [&](bf16x8 (&kC)[4], bf16x8 (&vC)[4],
                  bf16x8 (&kN)[4], bf16x8 (&vN)[4], int i) {
    const int jn = (i + 1) & 63;
    LOADW(kN, vN, jn);  // prefetch next window (no barrier; vmcnt-managed)

    // ---- S^T(i) = K @ Q^T: s[kvh][sl], lane(c,g) = S[q=c][kv=4g+r]
    f32x4 s[2][4];
#pragma unroll
    for (int kvh = 0; kvh < 2; ++kvh)
#pragma unroll
      for (int sl = 0; sl < 4; ++sl) {
        s[kvh][sl] = (f32x4){0.f, 0.f, 0.f, 0.f};
        s[kvh][sl] = MFMA32(kC[kvh * 2 + 0], aq[sl][0], s[kvh][sl]);
        s[kvh][sl] = MFMA32(kC[kvh * 2 + 1], aq[sl][1], s[kvh][sl]);
      }

    // ---- P = exp(S); lp accumulate; pack to PV A-frags (bf16x4)
    bf16x4 pa[2][4];
#pragma unroll
    for (int kvh = 0; kvh < 2; ++kvh)
#pragma unroll
      for (int sl = 0; sl < 4; ++sl) {
        float p0 = __expf(s[kvh][sl][0]), p1 = __expf(s[kvh][sl][1]);
        float p2 = __expf(s[kvh][sl][2]), p3 = __expf(s[kvh][sl][3]);
        lp[sl] += (p0 + p1) + (p2 + p3);
        unsigned r0 = cvt_pk_bf16(p0, p1), r1 = cvt_pk_bf16(p2, p3);
        uint2v u = {r0, r1};
        pa[kvh][sl] = __builtin_bit_cast(bf16x4, u);
      }

    // ---- PV(i): O += P @ V (k=16 mfma, V B-frag halves from vC b128s)
    __builtin_amdgcn_s_setprio(1);
#pragma unroll
    for (int df = 0; df < 4; ++df) {
      bf16x4 vlo = __builtin_shufflevector(vC[df], vC[df], 0, 1, 2, 3);
      bf16x4 vhi = __builtin_shufflevector(vC[df], vC[df], 4, 5, 6, 7);
#pragma unroll
      for (int sl = 0; sl < 4; ++sl) {
        o[sl][df] = MFMA16(pa[0][sl], vlo, o[sl][df]);
        o[sl][df] = MFMA16(pa[1][sl], vhi, o[sl][df]);
      }
    }
    __builtin_amdgcn_s_setprio(0);
  };

#pragma unroll 1
  for (int i = 0; i < 64; i += 2) {
    body(kA, vA, kB, vB, i);
    body(kB, vB, kA, vA, i + 1);
  }
#undef LOADW

  // ---- L: reduce lp over the 4 g-groups (kv mod-16 partials)
#pragma unroll
  for (int sl = 0; sl < 4; ++sl) {
    float v = lp[sl];
    v += __shfl_xor(v, 16);
    v += __shfl_xor(v, 32);
    lp[sl] = v;   // lane(c,g): L[q = sl*16 + c]
  }
  // redistribute: lane(c,g) needs L[q = sl*16 + 4g + r]
  if (l < 16) {
#pragma unroll
    for (int sl = 0; sl < 4; ++sl) Lsh[w][sl * 16 + l] = lp[sl];
  }
  __syncthreads();

  float* outb = out + ((size_t)b * N_ + q0) * D_;
#pragma unroll
  for (int sl = 0; sl < 4; ++sl)
#pragma unroll
    for (int r = 0; r < 4; ++r) {
      float inv = 1.0f / Lsh[w][sl * 16 + 4 * g + r];
      int q = sl * 16 + 4 * g + r;
#pragma unroll
      for (int df = 0; df < 4; ++df)
        outb[(size_t)q * D_ + w * 64 + df * 16 + c] = o[sl][df][r] * inv;
    }
}

// ---------------------------------------------------------------------------
extern "C" void kernel_launch(void* const* d_in, const int* in_sizes, int n_in,
                              void* d_out, int out_size, void* d_ws, size_t ws_size,
                              hipStream_t stream) {
  const float* X  = (const float*)d_in[0];
  const float* h  = (const float*)d_in[1];
  const float* WQ = (const float*)d_in[2];
  const float* bQ = (const float*)d_in[3];
  const float* WK = (const float*)d_in[4];
  const float* bK = (const float*)d_in[5];
  float* out = (float*)d_out;

  u16* Vf = (u16*)d_ws;                                // 16 MB
  u16* Qf = Vf + (size_t)B_ * D_ * N_;                 // 2 MB
  u16* Kf = Qf + (size_t)B_ * N_ * DK_;                // 2 MB

  vt_kernel<<<dim3(2048), dim3(256), 0, stream>>>(X, Vf);
  proj_kernel<<<dim3(256), dim3(256), 0, stream>>>(h, X, WQ, bQ, WK, bK, Qf, Kf);
  attn_kernel<<<dim3(256), dim3(512), 0, stream>>>(Qf, Kf, Vf, out);
}

// Round 15
// 106.762 us; speedup vs baseline: 1.0989x; 1.0989x over previous
//
#include <hip/hip_runtime.h>
#include <hip/hip_bf16.h>

#define B_ 8
#define N_ 2048
#define D_ 512
#define DK_ 64

typedef float f32x4 __attribute__((ext_vector_type(4)));
typedef short bf16x8 __attribute__((ext_vector_type(8)));
typedef unsigned int uint4v __attribute__((ext_vector_type(4)));
typedef unsigned long long u64x2 __attribute__((ext_vector_type(2)));
typedef unsigned short u16;

__device__ __forceinline__ u16 f2bf(float f) {
  union { float f; unsigned u; } v; v.f = f;
  unsigned r = v.u + 0x7FFFu + ((v.u >> 16) & 1u);  // RNE, inputs finite
  return (u16)(r >> 16);
}

#define MFMA32(a, b, cacc) __builtin_amdgcn_mfma_f32_16x16x32_bf16((a), (b), (cacc), 0, 0, 0)

// pack two f32 -> 2 bf16 in one dword (R13-validated construct)
__device__ __forceinline__ unsigned cvt_pk_bf16(float lo, float hi) {
  unsigned r;
  asm("v_cvt_pk_bf16_f32 %0, %1, %2" : "=v"(r) : "v"(lo), "v"(hi));
  return r;
}

// ===========================================================================
// Fragment layouts:
//  Qf/Kf: elem((b*128 + slab)*2 + ks)*512 + lane*8 + i
//         holds M[slab*16 + (lane&15)][ks*32 + (lane>>4)*8 + i]
//  Vf (permuted-kv K=32 B-frags): elem((b*32 + dt)*64 + j)*512 + lane*8 + i
//         holds X[j*32 + kvmap(lane>>4, i)][dt*16 + (lane&15)]
//         kvmap(g,i) = i<4 ? 4g+i : 16+4g+(i-4)
//  The kv permutation is identical on the S^T output regs (A-side) and Vf
//  (B-side), so PV contracts correctly with ONE mfma 16x16x32 per (sl, df).
// ===========================================================================

// ---------------------------------------------------------------------------
// Kernel 1 (validated R13): X f32 -> Vf bf16 (permuted-kv B-frags).
// ---------------------------------------------------------------------------
__global__ __launch_bounds__(256) void vt_kernel(const float* __restrict__ X,
                                                 u16* __restrict__ Vf) {
  int bid = blockIdx.x;
  int dt8 = bid & 7, nt = (bid >> 3) & 31, b = bid >> 8;
  int n0 = nt * 64, d0 = dt8 * 64;
  __shared__ u16 T[64 * 72];  // T[d_local][n_local]
  int t = threadIdx.x;
  const float* Xb = X + ((size_t)b * N_ + n0) * D_ + d0;
#pragma unroll
  for (int p = 0; p < 4; ++p) {
    int r = p * 16 + (t >> 4);      // n_local
    int c4 = (t & 15) * 4;          // d_local base
    f32x4 v = *reinterpret_cast<const f32x4*>(Xb + (size_t)r * D_ + c4);
#pragma unroll
    for (int j = 0; j < 4; ++j) T[(c4 + j) * 72 + r] = f2bf(v[j]);
  }
  __syncthreads();
  int w = t >> 6, l = t & 63, g = l >> 4, c = l & 15;
  // wave w -> dt = dt8*4 + w; two 32-kv windows jl=0,1 in this 64-n tile
#pragma unroll
  for (int jl = 0; jl < 2; ++jl) {
    u64x2 tmp;
    tmp[0] = *reinterpret_cast<const unsigned long long*>(
        &T[(w * 16 + c) * 72 + jl * 32 + 4 * g]);
    tmp[1] = *reinterpret_cast<const unsigned long long*>(
        &T[(w * 16 + c) * 72 + jl * 32 + 16 + 4 * g]);
    bf16x8 v = __builtin_bit_cast(bf16x8, tmp);
    *reinterpret_cast<bf16x8*>(
        Vf + (((size_t)(b * 32 + dt8 * 4 + w) * 64) + nt * 2 + jl) * 512 + l * 8) = v;
  }
}

// ---------------------------------------------------------------------------
// Kernel 2 (validated R13, QSCALE reverted to plain 1/8): Qf, Kf.
// ---------------------------------------------------------------------------
__global__ __launch_bounds__(256) void proj_kernel(
    const float* __restrict__ h, const float* __restrict__ X,
    const float* __restrict__ WQ, const float* __restrict__ bQ,
    const float* __restrict__ WK, const float* __restrict__ bK,
    u16* __restrict__ Qf, u16* __restrict__ Kf) {
  int bid = blockIdx.x;
  int b = bid & 7, nt = bid >> 3;
  int n0 = nt * 64;
  int t = threadIdx.x, w = t >> 6, l = t & 63, g = l >> 4, c = l & 15;
  int arow = n0 + w * 16 + c;
  const float* hrow = h + ((size_t)b * N_ + arow) * D_;
  const float* Xrow = X + ((size_t)b * N_ + arow) * D_;
  f32x4 accq[4], acck[4];
#pragma unroll
  for (int cf = 0; cf < 4; ++cf) {
    accq[cf] = (f32x4){0.f, 0.f, 0.f, 0.f};
    acck[cf] = (f32x4){0.f, 0.f, 0.f, 0.f};
  }
  for (int k0 = 0; k0 < D_; k0 += 32) {
    bf16x8 ah, ax;
    {
      f32x4 h0 = *reinterpret_cast<const f32x4*>(hrow + k0 + 8 * g);
      f32x4 h1 = *reinterpret_cast<const f32x4*>(hrow + k0 + 8 * g + 4);
      f32x4 x0 = *reinterpret_cast<const f32x4*>(Xrow + k0 + 8 * g);
      f32x4 x1 = *reinterpret_cast<const f32x4*>(Xrow + k0 + 8 * g + 4);
#pragma unroll
      for (int i = 0; i < 4; ++i) {
        ah[i] = (short)f2bf(h0[i]); ah[i + 4] = (short)f2bf(h1[i]);
        ax[i] = (short)f2bf(x0[i]); ax[i + 4] = (short)f2bf(x1[i]);
      }
    }
#pragma unroll
    for (int cf = 0; cf < 4; ++cf) {
      bf16x8 bq, bk;
#pragma unroll
      for (int i = 0; i < 8; ++i) {
        int kk = k0 + 8 * g + i;
        bq[i] = (short)f2bf(WQ[(size_t)kk * DK_ + cf * 16 + c]);
        bk[i] = (short)f2bf(WK[(size_t)kk * DK_ + cf * 16 + c]);
      }
      accq[cf] = MFMA32(ah, bq, accq[cf]);
      acck[cf] = MFMA32(ax, bk, acck[cf]);
    }
  }
#pragma unroll
  for (int cf = 0; cf < 4; ++cf) {
    float vq = bQ[cf * 16 + c], vk = bK[cf * 16 + c];
    int ks = cf >> 1;
    int g2 = ((cf & 1) * 16 + c) >> 3;
    int i2 = c & 7;
#pragma unroll
    for (int r = 0; r < 4; ++r) {
      size_t e = ((size_t)(b * 128 + nt * 4 + w) * 2 + ks) * 512 +
                 (g2 * 16 + 4 * g + r) * 8 + i2;
      Qf[e] = f2bf((accq[cf][r] + vq) * 0.125f);
      Kf[e] = f2bf(acck[cf][r] + vk);
    }
  }
}

// ---------------------------------------------------------------------------
// attn: barrier-free register-softmax (R13 skeleton). 256 blocks x 8 waves;
// wave = 64q x 64d, fully independent (no LDS/barrier in loop).
// S^T = mfma(A=K, B=Q): lane(c,g) -> S[q=c][kv=kvh*16+4g+r].
// P packed (cvt_pk, R13-validated) as permuted-kv K=32 A-frag; Vf is the
// matching B-frag -> PV = 16 x mfma_16x16x32 per window (the R14 win).
// exp via __expf (compiler-managed v_mul+v_exp hazards; R14's raw v_exp asm
// produced NaN -- inline-asm trans-op hazard, rule #18 family).
// ---------------------------------------------------------------------------
__global__ __launch_bounds__(512, 2) void attn_kernel(
    const u16* __restrict__ Qf, const u16* __restrict__ Kf,
    const u16* __restrict__ Vf, float* __restrict__ out) {
  int bid = blockIdx.x;
  int b = bid & 7, qt = bid >> 3;
  int q0 = qt * 64;
  int t = threadIdx.x, w = t >> 6, l = t & 63, g = l >> 4, c = l & 15;

  __shared__ float Lsh[8][64];

  // Q B-frags, resident: aq[slab][ks]
  bf16x8 aq[4][2];
#pragma unroll
  for (int sl = 0; sl < 4; ++sl)
#pragma unroll
    for (int ks = 0; ks < 2; ++ks)
      aq[sl][ks] = *reinterpret_cast<const bf16x8*>(
          Qf + ((size_t)(b * 128 + qt * 4 + sl) * 2 + ks) * 512 + l * 8);

  f32x4 o[4][4];
#pragma unroll
  for (int sl = 0; sl < 4; ++sl)
#pragma unroll
    for (int df = 0; df < 4; ++df) o[sl][df] = (f32x4){0.f, 0.f, 0.f, 0.f};
  float lp[4] = {0.f, 0.f, 0.f, 0.f};

  // K frag (window j, kvh, ks): Kbase + ((j*2+kvh)*2+ks)*512
  const u16* Kbase = Kf + ((size_t)b * 256) * 512 + l * 8;
  // V frag (df, window j): Vbase + (df*64 + j)*512
  const u16* Vbase = Vf + ((size_t)(b * 32 + w * 4) * 64) * 512 + l * 8;

  bf16x8 kA[4], kB[4], vA[4], vB[4];

#define LOADW(kT, vT, j)                                                      \
  do {                                                                        \
    _Pragma("unroll") for (int kv2 = 0; kv2 < 4; ++kv2)                       \
        kT[kv2] = *reinterpret_cast<const bf16x8*>(                           \
            Kbase + (size_t)(((j) * 2 + (kv2 >> 1)) * 2 + (kv2 & 1)) * 512);  \
    _Pragma("unroll") for (int df = 0; df < 4; ++df)                          \
        vT[df] = *reinterpret_cast<const bf16x8*>(                            \
            Vbase + (size_t)(df * 64 + (j)) * 512);                           \
  } while (0)

  LOADW(kA, vA, 0);

  auto body = [&](bf16x8 (&kC)[4], bf16x8 (&vC)[4],
                  bf16x8 (&kN)[4], bf16x8 (&vN)[4], int i) {
    const int jn = (i + 1) & 63;
    LOADW(kN, vN, jn);  // prefetch next window (no barrier; vmcnt-managed)

    // ---- S^T(i) = K @ Q^T: s[kvh][sl], lane(c,g) = S[q=c][kv=kvh*16+4g+r]
    f32x4 s[2][4];
#pragma unroll
    for (int kvh = 0; kvh < 2; ++kvh)
#pragma unroll
      for (int sl = 0; sl < 4; ++sl) {
        s[kvh][sl] = (f32x4){0.f, 0.f, 0.f, 0.f};
        s[kvh][sl] = MFMA32(kC[kvh * 2 + 0], aq[sl][0], s[kvh][sl]);
        s[kvh][sl] = MFMA32(kC[kvh * 2 + 1], aq[sl][1], s[kvh][sl]);
      }

    // ---- P = exp(S); lp; pack permuted-kv K=32 A-frags
    bf16x8 pa8[4];
#pragma unroll
    for (int sl = 0; sl < 4; ++sl) {
      float p00 = __expf(s[0][sl][0]), p01 = __expf(s[0][sl][1]);
      float p02 = __expf(s[0][sl][2]), p03 = __expf(s[0][sl][3]);
      float p10 = __expf(s[1][sl][0]), p11 = __expf(s[1][sl][1]);
      float p12 = __expf(s[1][sl][2]), p13 = __expf(s[1][sl][3]);
      lp[sl] += ((p00 + p01) + (p02 + p03)) + ((p10 + p11) + (p12 + p13));
      uint4v u = {cvt_pk_bf16(p00, p01), cvt_pk_bf16(p02, p03),
                  cvt_pk_bf16(p10, p11), cvt_pk_bf16(p12, p13)};
      pa8[sl] = __builtin_bit_cast(bf16x8, u);
    }

    // ---- PV(i): O += P @ V, one K=32 mfma per (sl, df)
    __builtin_amdgcn_s_setprio(1);
#pragma unroll
    for (int df = 0; df < 4; ++df)
#pragma unroll
      for (int sl = 0; sl < 4; ++sl)
        o[sl][df] = MFMA32(pa8[sl], vC[df], o[sl][df]);
    __builtin_amdgcn_s_setprio(0);
  };

#pragma unroll 1
  for (int i = 0; i < 64; i += 2) {
    body(kA, vA, kB, vB, i);
    body(kB, vB, kA, vA, i + 1);
  }
#undef LOADW

  // ---- L: reduce lp over the 4 g-groups (kv partials)
#pragma unroll
  for (int sl = 0; sl < 4; ++sl) {
    float v = lp[sl];
    v += __shfl_xor(v, 16);
    v += __shfl_xor(v, 32);
    lp[sl] = v;   // lane(c,g): L[q = sl*16 + c]
  }
  // redistribute: lane(c,g) needs L[q = sl*16 + 4g + r]
  if (l < 16) {
#pragma unroll
    for (int sl = 0; sl < 4; ++sl) Lsh[w][sl * 16 + l] = lp[sl];
  }
  __syncthreads();

  float* outb = out + ((size_t)b * N_ + q0) * D_;
#pragma unroll
  for (int sl = 0; sl < 4; ++sl)
#pragma unroll
    for (int r = 0; r < 4; ++r) {
      float inv = 1.0f / Lsh[w][sl * 16 + 4 * g + r];
      int q = sl * 16 + 4 * g + r;
#pragma unroll
      for (int df = 0; df < 4; ++df)
        outb[(size_t)q * D_ + w * 64 + df * 16 + c] = o[sl][df][r] * inv;
    }
}

// ---------------------------------------------------------------------------
extern "C" void kernel_launch(void* const* d_in, const int* in_sizes, int n_in,
                              void* d_out, int out_size, void* d_ws, size_t ws_size,
                              hipStream_t stream) {
  const float* X  = (const float*)d_in[0];
  const float* h  = (const float*)d_in[1];
  const float* WQ = (const float*)d_in[2];
  const float* bQ = (const float*)d_in[3];
  const float* WK = (const float*)d_in[4];
  const float* bK = (const float*)d_in[5];
  float* out = (float*)d_out;

  u16* Vf = (u16*)d_ws;                                // 16 MB
  u16* Qf = Vf + (size_t)B_ * D_ * N_;                 // 2 MB
  u16* Kf = Qf + (size_t)B_ * N_ * DK_;                // 2 MB

  vt_kernel<<<dim3(2048), dim3(256), 0, stream>>>(X, Vf);
  proj_kernel<<<dim3(256), dim3(256), 0, stream>>>(h, X, WQ, bQ, WK, bK, Qf, Kf);
  attn_kernel<<<dim3(256), dim3(512), 0, stream>>>(Qf, Kf, Vf, out);
}

// Round 17
// 83.879 us; speedup vs baseline: 1.3986x; 1.2728x over previous
//
#include <hip/hip_runtime.h>
#include <hip/hip_bf16.h>

#define B_ 8
#define N_ 2048
#define D_ 512
#define DK_ 64

typedef float f32x4 __attribute__((ext_vector_type(4)));
typedef short bf16x8 __attribute__((ext_vector_type(8)));
typedef unsigned short u16;

__device__ __forceinline__ u16 f2bf(float f) {
  union { float f; unsigned u; } v; v.f = f;
  unsigned r = v.u + 0x7FFFu + ((v.u >> 16) & 1u);  // RNE, inputs finite
  return (u16)(r >> 16);
}

#define MFMA32(a, b, cacc) __builtin_amdgcn_mfma_f32_16x16x32_bf16((a), (b), (cacc), 0, 0, 0)

// lgkm-only barrier (validated R4/R10 incl. graph-replay revalidation):
// orders LDS ops across the barrier WITHOUT draining vmcnt; all in-flight
// vmem targets per-wave registers (no cross-wave hazard).
#define BARRIER_LGKM() do {                                   \
    asm volatile("s_waitcnt lgkmcnt(0)" ::: "memory");        \
    __builtin_amdgcn_s_barrier();                             \
    asm volatile("" ::: "memory");                            \
  } while (0)

// ===========================================================================
// Fragment layouts (every attn global load = 64 lanes x 16B contiguous 1KB):
//  Qf/Kf: elem((b*128 + slab)*2 + ks)*512 + lane*8 + i
//         holds  M[slab*16 + (lane&15)][ks*32 + (lane>>4)*8 + i]
//  Vf:    elem(((b*32 + dt)*32 + nt)*2 + ks)*512 + lane*8 + i
//         holds  X[nt*64 + ks*32 + (lane>>4)*8 + i][dt*16 + (lane&15)]
// ===========================================================================

// ---------------------------------------------------------------------------
// Kernel 1 (validated R6-R10): X f32 -> Vf bf16 frag layout.
// ---------------------------------------------------------------------------
__global__ __launch_bounds__(256) void vt_kernel(const float* __restrict__ X,
                                                 u16* __restrict__ Vf) {
  int bid = blockIdx.x;
  int dt = bid & 7, nt = (bid >> 3) & 31, b = bid >> 8;
  int n0 = nt * 64, d0 = dt * 64;
  __shared__ u16 T[64 * 72];  // T[d_local][n_local]
  int t = threadIdx.x;
  const float* Xb = X + ((size_t)b * N_ + n0) * D_ + d0;
#pragma unroll
  for (int p = 0; p < 4; ++p) {
    int r = p * 16 + (t >> 4);      // n_local
    int c4 = (t & 15) * 4;          // d_local base
    f32x4 v = *reinterpret_cast<const f32x4*>(Xb + (size_t)r * D_ + c4);
#pragma unroll
    for (int j = 0; j < 4; ++j) T[(c4 + j) * 72 + r] = f2bf(v[j]);
  }
  __syncthreads();
  int w = t >> 6, l = t & 63, g = l >> 4, c = l & 15;
#pragma unroll
  for (int ks = 0; ks < 2; ++ks) {
    bf16x8 v = *reinterpret_cast<const bf16x8*>(&T[(w * 16 + c) * 72 + ks * 32 + 8 * g]);
    *reinterpret_cast<bf16x8*>(
        Vf + (((size_t)(b * 32 + dt * 4 + w) * 32 + nt) * 2 + ks) * 512 + l * 8) = v;
  }
}

// ---------------------------------------------------------------------------
// Kernel 2 (validated R6-R10): Qf = (h@WQ + bQ)/8, Kf = X@WK + bK.
// ---------------------------------------------------------------------------
__global__ __launch_bounds__(256) void proj_kernel(
    const float* __restrict__ h, const float* __restrict__ X,
    const float* __restrict__ WQ, const float* __restrict__ bQ,
    const float* __restrict__ WK, const float* __restrict__ bK,
    u16* __restrict__ Qf, u16* __restrict__ Kf) {
  int bid = blockIdx.x;
  int b = bid & 7, nt = bid >> 3;
  int n0 = nt * 64;
  int t = threadIdx.x, w = t >> 6, l = t & 63, g = l >> 4, c = l & 15;
  int arow = n0 + w * 16 + c;
  const float* hrow = h + ((size_t)b * N_ + arow) * D_;
  const float* Xrow = X + ((size_t)b * N_ + arow) * D_;
  f32x4 accq[4], acck[4];
#pragma unroll
  for (int cf = 0; cf < 4; ++cf) {
    accq[cf] = (f32x4){0.f, 0.f, 0.f, 0.f};
    acck[cf] = (f32x4){0.f, 0.f, 0.f, 0.f};
  }
  for (int k0 = 0; k0 < D_; k0 += 32) {
    bf16x8 ah, ax;
    {
      f32x4 h0 = *reinterpret_cast<const f32x4*>(hrow + k0 + 8 * g);
      f32x4 h1 = *reinterpret_cast<const f32x4*>(hrow + k0 + 8 * g + 4);
      f32x4 x0 = *reinterpret_cast<const f32x4*>(Xrow + k0 + 8 * g);
      f32x4 x1 = *reinterpret_cast<const f32x4*>(Xrow + k0 + 8 * g + 4);
#pragma unroll
      for (int i = 0; i < 4; ++i) {
        ah[i] = (short)f2bf(h0[i]); ah[i + 4] = (short)f2bf(h1[i]);
        ax[i] = (short)f2bf(x0[i]); ax[i + 4] = (short)f2bf(x1[i]);
      }
    }
#pragma unroll
    for (int cf = 0; cf < 4; ++cf) {
      bf16x8 bq, bk;
#pragma unroll
      for (int i = 0; i < 8; ++i) {
        int kk = k0 + 8 * g + i;
        bq[i] = (short)f2bf(WQ[(size_t)kk * DK_ + cf * 16 + c]);
        bk[i] = (short)f2bf(WK[(size_t)kk * DK_ + cf * 16 + c]);
      }
      accq[cf] = MFMA32(ah, bq, accq[cf]);
      acck[cf] = MFMA32(ax, bk, acck[cf]);
    }
  }
#pragma unroll
  for (int cf = 0; cf < 4; ++cf) {
    float vq = bQ[cf * 16 + c], vk = bK[cf * 16 + c];
    int ks = cf >> 1;
    int g2 = ((cf & 1) * 16 + c) >> 3;
    int i2 = c & 7;
#pragma unroll
    for (int r = 0; r < 4; ++r) {
      size_t e = ((size_t)(b * 128 + nt * 4 + w) * 2 + ks) * 512 +
                 (g2 * 16 + 4 * g + r) * 8 + i2;
      Qf[e] = f2bf((accq[cf][r] + vq) * 0.125f);
      Kf[e] = f2bf(acck[cf][r] + vk);
    }
  }
}

// ---------------------------------------------------------------------------
// attn: R8's validated kernel (512 blocks x 256 thr, 64q x 256d, 2 blocks/CU
// de-phasing, stride-76 Plds = 0 bank conflicts, prefetch-after-barrier)
// with EXACTLY ONE change: __syncthreads -> lgkm-only barrier, so the
// register prefetch issued after the previous barrier is never drained
// (R8 paid a full vmcnt(0) drain per window).
// ---------------------------------------------------------------------------
__global__ __launch_bounds__(256, 2) void attn_kernel(
    const u16* __restrict__ Qf, const u16* __restrict__ Kf,
    const u16* __restrict__ Vf, float* __restrict__ out) {
  int bid = blockIdx.x;
  int b = bid & 7, dh = (bid >> 3) & 1, qt = bid >> 4;
  int q0 = qt * 64;
  int t = threadIdx.x, w = t >> 6, l = t & 63, g = l >> 4, c = l & 15;
  int qh = w >> 1, kq = w & 1;          // S-slab coords (2x2)

  __shared__ u16 Plds[2][64][76];       // P double buffer [q 64][kv 64]
  __shared__ float Lp[2][64];

  // resident Q A-frags: slab = qt*4 + qh*2 + qf
  bf16x8 aq[2][2];
#pragma unroll
  for (int qf = 0; qf < 2; ++qf)
#pragma unroll
    for (int ks = 0; ks < 2; ++ks)
      aq[qf][ks] = *reinterpret_cast<const bf16x8*>(
          Qf + ((size_t)(b * 128 + qt * 4 + qh * 2 + qf) * 2 + ks) * 512 + l * 8);

  f32x4 o[4][4];
#pragma unroll
  for (int a = 0; a < 4; ++a)
#pragma unroll
    for (int d = 0; d < 4; ++d) o[a][d] = (f32x4){0.f, 0.f, 0.f, 0.f};
  float lp[2][4];
#pragma unroll
  for (int a = 0; a < 2; ++a)
#pragma unroll
    for (int r = 0; r < 4; ++r) lp[a][r] = 0.f;

  // frag-line bases (u16 elems)
  // K slab for tile kvt, sub kf: kvt*4 + kq*2 + kf
  const u16* Kbase = Kf + (size_t)(b * 128 + kq * 2) * 2 * 512 + l * 8;
  // V tile dt = dh*16 + w*4 + df
  const u16* Vbase = Vf + ((size_t)(b * 32 + dh * 16 + w * 4) * 32) * 2 * 512 + l * 8;

  bf16x8 vA[8], vB[8], kA[4], kB[4];
#pragma unroll
  for (int kf = 0; kf < 2; ++kf)
#pragma unroll
    for (int ks = 0; ks < 2; ++ks)
      kA[kf * 2 + ks] = *reinterpret_cast<const bf16x8*>(
          Kbase + ((size_t)kf * 2 + ks) * 512);
#pragma unroll
  for (int ks = 0; ks < 2; ++ks)
#pragma unroll
    for (int df = 0; df < 4; ++df)
      vA[ks * 4 + df] = *reinterpret_cast<const bf16x8*>(
          Vbase + ((size_t)df * 32 * 2 + ks) * 512);

  auto body = [&](bf16x8 (&vC)[8], bf16x8 (&kC)[4],
                  bf16x8 (&vN)[8], bf16x8 (&kN)[4], int i) {
    const int pb = i & 1;
    const int kvn = (i + 1) & 31;

    // ---- S = Q/8 @ K^T for this wave's [32q][32kv] slab (register-only)
    f32x4 s[2][2];
#pragma unroll
    for (int qf = 0; qf < 2; ++qf)
#pragma unroll
      for (int kf = 0; kf < 2; ++kf) {
        s[qf][kf] = (f32x4){0.f, 0.f, 0.f, 0.f};
        s[qf][kf] = MFMA32(aq[qf][0], kC[kf * 2 + 0], s[qf][kf]);
        s[qf][kf] = MFMA32(aq[qf][1], kC[kf * 2 + 1], s[qf][kf]);
      }

    // ---- P = exp(S), partial sums, write P slab (bf16)
#pragma unroll
    for (int qf = 0; qf < 2; ++qf)
#pragma unroll
      for (int kf = 0; kf < 2; ++kf)
#pragma unroll
        for (int r = 0; r < 4; ++r) {
          float p = __expf(s[qf][kf][r]);
          lp[qf][r] += p;
          Plds[pb][qh * 32 + qf * 16 + 4 * g + r][kq * 32 + kf * 16 + c] = f2bf(p);
        }

    // ---- lgkm-only barrier (the one change vs R8): P writes visible,
    // prefetch issued after the PREVIOUS barrier stays in flight.
    BARRIER_LGKM();

    // ---- issue next-tile K/V frag loads (contiguous 1KB each)
#pragma unroll
    for (int kf = 0; kf < 2; ++kf)
#pragma unroll
      for (int ks = 0; ks < 2; ++ks)
        kN[kf * 2 + ks] = *reinterpret_cast<const bf16x8*>(
            Kbase + ((size_t)(kvn * 4 + kf) * 2 + ks) * 512);
#pragma unroll
    for (int ks = 0; ks < 2; ++ks)
#pragma unroll
      for (int df = 0; df < 4; ++df)
        vN[ks * 4 + df] = *reinterpret_cast<const bf16x8*>(
            Vbase + (((size_t)df * 32 + kvn) * 2 + ks) * 512);

    // ---- O += P @ V  (P from LDS, V from registers), prioritized
    bf16x8 pa0, pa1, pa2, pa3;
    __builtin_amdgcn_s_setprio(1);
#pragma unroll
    for (int ks = 0; ks < 2; ++ks) {
      pa0 = *reinterpret_cast<const bf16x8*>(&Plds[pb][c][ks * 32 + 8 * g]);
      pa1 = *reinterpret_cast<const bf16x8*>(&Plds[pb][16 + c][ks * 32 + 8 * g]);
      pa2 = *reinterpret_cast<const bf16x8*>(&Plds[pb][32 + c][ks * 32 + 8 * g]);
      pa3 = *reinterpret_cast<const bf16x8*>(&Plds[pb][48 + c][ks * 32 + 8 * g]);
#pragma unroll
      for (int df = 0; df < 4; ++df) {
        o[0][df] = MFMA32(pa0, vC[ks * 4 + df], o[0][df]);
        o[1][df] = MFMA32(pa1, vC[ks * 4 + df], o[1][df]);
        o[2][df] = MFMA32(pa2, vC[ks * 4 + df], o[2][df]);
        o[3][df] = MFMA32(pa3, vC[ks * 4 + df], o[3][df]);
      }
    }
    __builtin_amdgcn_s_setprio(0);
  };

#pragma unroll 1
  for (int i = 0; i < 32; i += 2) {
    body(vA, kA, vB, kB, i);
    body(vB, kB, vA, kA, i + 1);
  }

  // ---- denominator: reduce lp over 16 c-lanes, combine across kq waves
#pragma unroll
  for (int qf = 0; qf < 2; ++qf)
#pragma unroll
    for (int r = 0; r < 4; ++r) {
      float v = lp[qf][r];
      v += __shfl_xor(v, 1); v += __shfl_xor(v, 2);
      v += __shfl_xor(v, 4); v += __shfl_xor(v, 8);
      lp[qf][r] = v;
    }
  if (c == 0) {
#pragma unroll
    for (int qf = 0; qf < 2; ++qf)
#pragma unroll
      for (int r = 0; r < 4; ++r)
        Lp[kq][qh * 32 + qf * 16 + 4 * g + r] = lp[qf][r];
  }
  __syncthreads();  // epilogue: full barrier once (drains last prefetch too)

  float* outb = out + ((size_t)b * N_ + q0) * D_ + dh * 256;
#pragma unroll
  for (int qf2 = 0; qf2 < 4; ++qf2)
#pragma unroll
    for (int r = 0; r < 4; ++r) {
      int ql = qf2 * 16 + 4 * g + r;
      float L = Lp[0][ql] + Lp[1][ql];
      float inv = 1.0f / L;
#pragma unroll
      for (int df = 0; df < 4; ++df)
        outb[(size_t)ql * D_ + w * 64 + df * 16 + c] = o[qf2][df][r] * inv;
    }
}

// ---------------------------------------------------------------------------
extern "C" void kernel_launch(void* const* d_in, const int* in_sizes, int n_in,
                              void* d_out, int out_size, void* d_ws, size_t ws_size,
                              hipStream_t stream) {
  const float* X  = (const float*)d_in[0];
  const float* h  = (const float*)d_in[1];
  const float* WQ = (const float*)d_in[2];
  const float* bQ = (const float*)d_in[3];
  const float* WK = (const float*)d_in[4];
  const float* bK = (const float*)d_in[5];
  float* out = (float*)d_out;

  u16* Vf = (u16*)d_ws;                                // 16 MB
  u16* Qf = Vf + (size_t)B_ * D_ * N_;                 // 2 MB
  u16* Kf = Qf + (size_t)B_ * N_ * DK_;                // 2 MB

  vt_kernel<<<dim3(2048), dim3(256), 0, stream>>>(X, Vf);
  proj_kernel<<<dim3(256), dim3(256), 0, stream>>>(h, X, WQ, bQ, WK, bK, Qf, Kf);
  attn_kernel<<<dim3(512), dim3(256), 0, stream>>>(Qf, Kf, Vf, out);
}

// Round 18
// 76.983 us; speedup vs baseline: 1.5239x; 1.0896x over previous
//
#include <hip/hip_runtime.h>
#include <hip/hip_bf16.h>

#define B_ 8
#define N_ 2048
#define D_ 512
#define DK_ 64

typedef float f32x4 __attribute__((ext_vector_type(4)));
typedef short bf16x8 __attribute__((ext_vector_type(8)));
typedef unsigned short u16;

__device__ __forceinline__ u16 f2bf(float f) {
  union { float f; unsigned u; } v; v.f = f;
  unsigned r = v.u + 0x7FFFu + ((v.u >> 16) & 1u);  // RNE, inputs finite
  return (u16)(r >> 16);
}

#define MFMA32(a, b, cacc) __builtin_amdgcn_mfma_f32_16x16x32_bf16((a), (b), (cacc), 0, 0, 0)

// lgkm-only barrier (validated R4/R10/R17 incl. graph-replay revalidation):
// orders LDS ops across the barrier WITHOUT draining vmcnt; all in-flight
// vmem targets per-wave registers (no cross-wave hazard).
#define BARRIER_LGKM() do {                                   \
    asm volatile("s_waitcnt lgkmcnt(0)" ::: "memory");        \
    __builtin_amdgcn_s_barrier();                             \
    asm volatile("" ::: "memory");                            \
  } while (0)

// ===========================================================================
// Fragment layouts (every attn global load = 64 lanes x 16B contiguous 1KB):
//  Qf/Kf: elem((b*128 + slab)*2 + ks)*512 + lane*8 + i
//         holds  M[slab*16 + (lane&15)][ks*32 + (lane>>4)*8 + i]
//  Vf:    elem(((b*32 + dt)*32 + nt)*2 + ks)*512 + lane*8 + i
//         holds  X[nt*64 + ks*32 + (lane>>4)*8 + i][dt*16 + (lane&15)]
// ===========================================================================

// ---------------------------------------------------------------------------
// prep (FUSED vt+proj): one pass over X.  grid 256 = b(8) x nt(32), 256 thr.
//  Qf = (h@WQ + bQ)/8, Kf = X@WK + bK (MFMA, frag stores -- R6-R17 indexing)
//  Vf = X^T bf16 frag layout (X tile stashed bf16 in LDS during the k-loop;
//       one full __syncthreads before cross-wave reads).
// Saves vt's separate 64MB cold HBM read of X.
// ---------------------------------------------------------------------------
__global__ __launch_bounds__(256) void prep_kernel(
    const float* __restrict__ h, const float* __restrict__ X,
    const float* __restrict__ WQ, const float* __restrict__ bQ,
    const float* __restrict__ WK, const float* __restrict__ bK,
    u16* __restrict__ Qf, u16* __restrict__ Kf, u16* __restrict__ Vf) {
  int bid = blockIdx.x;
  int b = bid & 7, nt = bid >> 3;
  int n0 = nt * 64;
  int t = threadIdx.x, w = t >> 6, l = t & 63, g = l >> 4, c = l & 15;

  __shared__ u16 Xb16[64][520];   // X tile bf16 [n_local][d]; 65 KB; rows are
                                  // wave-private during the k-loop.

  int arow = n0 + w * 16 + c;
  const float* hrow = h + ((size_t)b * N_ + arow) * D_;
  const float* Xrow = X + ((size_t)b * N_ + arow) * D_;
  f32x4 accq[4], acck[4];
#pragma unroll
  for (int cf = 0; cf < 4; ++cf) {
    accq[cf] = (f32x4){0.f, 0.f, 0.f, 0.f};
    acck[cf] = (f32x4){0.f, 0.f, 0.f, 0.f};
  }
  for (int k0 = 0; k0 < D_; k0 += 32) {
    bf16x8 ah, ax;
    {
      f32x4 h0 = *reinterpret_cast<const f32x4*>(hrow + k0 + 8 * g);
      f32x4 h1 = *reinterpret_cast<const f32x4*>(hrow + k0 + 8 * g + 4);
      f32x4 x0 = *reinterpret_cast<const f32x4*>(Xrow + k0 + 8 * g);
      f32x4 x1 = *reinterpret_cast<const f32x4*>(Xrow + k0 + 8 * g + 4);
#pragma unroll
      for (int i = 0; i < 4; ++i) {
        ah[i] = (short)f2bf(h0[i]); ah[i + 4] = (short)f2bf(h1[i]);
        ax[i] = (short)f2bf(x0[i]); ax[i + 4] = (short)f2bf(x1[i]);
      }
    }
    // stash bf16 X row-chunk (row w*16+c: written only by this lane's wave)
    *reinterpret_cast<bf16x8*>(&Xb16[w * 16 + c][k0 + 8 * g]) = ax;
#pragma unroll
    for (int cf = 0; cf < 4; ++cf) {
      bf16x8 bq, bk;
#pragma unroll
      for (int i = 0; i < 8; ++i) {
        int kk = k0 + 8 * g + i;
        bq[i] = (short)f2bf(WQ[(size_t)kk * DK_ + cf * 16 + c]);
        bk[i] = (short)f2bf(WK[(size_t)kk * DK_ + cf * 16 + c]);
      }
      accq[cf] = MFMA32(ah, bq, accq[cf]);
      acck[cf] = MFMA32(ax, bk, acck[cf]);
    }
  }

  // Qf/Kf frag stores (independent of LDS; R6-R17 validated indexing)
#pragma unroll
  for (int cf = 0; cf < 4; ++cf) {
    float vq = bQ[cf * 16 + c], vk = bK[cf * 16 + c];
    int ks = cf >> 1;
    int g2 = ((cf & 1) * 16 + c) >> 3;
    int i2 = c & 7;
#pragma unroll
    for (int r = 0; r < 4; ++r) {
      size_t e = ((size_t)(b * 128 + nt * 4 + w) * 2 + ks) * 512 +
                 (g2 * 16 + 4 * g + r) * 8 + i2;
      Qf[e] = f2bf((accq[cf][r] + vq) * 0.125f);
      Kf[e] = f2bf(acck[cf][r] + vk);
    }
  }

  __syncthreads();  // full barrier: all Xb16 writes visible to all waves

  // Vf frag stores: wave w handles dt = w*8 .. w*8+7 (R6-R17 Vf layout)
#pragma unroll
  for (int dtl = 0; dtl < 8; ++dtl) {
    int dt = w * 8 + dtl;
#pragma unroll
    for (int ks = 0; ks < 2; ++ks) {
      bf16x8 v;
#pragma unroll
      for (int i = 0; i < 8; ++i) v[i] = Xb16[ks * 32 + 8 * g + i][dt * 16 + c];
      *reinterpret_cast<bf16x8*>(
          Vf + (((size_t)(b * 32 + dt) * 32 + nt) * 2 + ks) * 512 + l * 8) = v;
    }
  }
}

// ---------------------------------------------------------------------------
// attn: R10's validated kernel, byte-identical (52.0 us, passed incl.
// graph-replay revalidation). 256 blocks x 512 threads (8 waves),
// 64q x 512d, KVBLK=32, K/V register-buffered 4-deep, lgkm-only barrier.
// ---------------------------------------------------------------------------
__global__ __launch_bounds__(512, 1) void attn_kernel(
    const u16* __restrict__ Qf, const u16* __restrict__ Kf,
    const u16* __restrict__ Vf, float* __restrict__ out) {
  int bid = blockIdx.x;
  int b = bid & 7, qt = bid >> 3;
  int q0 = qt * 64;
  int t = threadIdx.x, w = t >> 6, l = t & 63, g = l >> 4, c = l & 15;
  int qh = w >> 1, kq = w & 1;

  __shared__ u16 Plds[2][64][40];   // P dbuf [q 64][kv 32], stride 40 u16
  __shared__ float Lp[2][64];

  // resident Q A-frags for slab qt*4+qh
  bf16x8 aq[2];
#pragma unroll
  for (int ks = 0; ks < 2; ++ks)
    aq[ks] = *reinterpret_cast<const bf16x8*>(
        Qf + ((size_t)(b * 128 + qt * 4 + qh) * 2 + ks) * 512 + l * 8);

  f32x4 o[4][4];
#pragma unroll
  for (int a = 0; a < 4; ++a)
#pragma unroll
    for (int d = 0; d < 4; ++d) o[a][d] = (f32x4){0.f, 0.f, 0.f, 0.f};
  float lp[4] = {0.f, 0.f, 0.f, 0.f};

  // K frag (tile kvt, ks): elem (b*256 + 4*kvt + 2*kq + ks)*512 + l*8
  const u16* Kbase = Kf + ((size_t)(b * 256 + 2 * kq)) * 512 + l * 8;
  // V frag (f, tile kvt): elem ((b*32 + w*4 + f)*64 + kvt)*512 + l*8
  const u16* Vbase = Vf + ((size_t)(b * 32 + w * 4) * 64) * 512 + l * 8;

  bf16x8 kbuf[4][2], vbuf[4][4];

  // ---- prologue: stage tiles 0..2 (3-deep), S(0), P(0)->buf0, barrier
#pragma unroll
  for (int j = 0; j < 3; ++j) {
#pragma unroll
    for (int ks = 0; ks < 2; ++ks)
      kbuf[j][ks] = *reinterpret_cast<const bf16x8*>(
          Kbase + (size_t)(4 * j + ks) * 512);
#pragma unroll
    for (int f = 0; f < 4; ++f)
      vbuf[j][f] = *reinterpret_cast<const bf16x8*>(
          Vbase + (size_t)(f * 64 + j) * 512);
  }
  {
    f32x4 s = (f32x4){0.f, 0.f, 0.f, 0.f};
    s = MFMA32(aq[0], kbuf[0][0], s);
    s = MFMA32(aq[1], kbuf[0][1], s);
#pragma unroll
    for (int r = 0; r < 4; ++r) {
      float p = __expf(s[r]); lp[r] += p;
      Plds[0][qh * 16 + 4 * g + r][kq * 16 + c] = f2bf(p);
    }
  }
  BARRIER_LGKM();

  // window i: load tile (i+3) -> kL/vL; S(i+1) from kS; P(i+1)->buf[(i+1)&1];
  // PV(i) from Plds[i&1] + vR; lgkm-only barrier.
  auto body = [&](bf16x8 (&kS)[2], bf16x8 (&kL)[2],
                  bf16x8 (&vR)[4], bf16x8 (&vL)[4], int i) {
    const int kvL = (i + 3) & 63;
    const int pbW = (i + 1) & 1, pbR = i & 1;

    // issue prefetch: K first (consumed 2 windows out), then V (3 windows)
#pragma unroll
    for (int ks = 0; ks < 2; ++ks)
      kL[ks] = *reinterpret_cast<const bf16x8*>(
          Kbase + (size_t)(4 * kvL + ks) * 512);
#pragma unroll
    for (int f = 0; f < 4; ++f)
      vL[f] = *reinterpret_cast<const bf16x8*>(
          Vbase + (size_t)(f * 64 + kvL) * 512);

    // ---- S(i+1): one 16q x 16kv C-tile per wave (register-only)
    f32x4 s = (f32x4){0.f, 0.f, 0.f, 0.f};
    s = MFMA32(aq[0], kS[0], s);
    s = MFMA32(aq[1], kS[1], s);

    // ---- exp(i+1) + P-write to buf[pbW]
#pragma unroll
    for (int r = 0; r < 4; ++r) {
      float p = __expf(s[r]); lp[r] += p;
      Plds[pbW][qh * 16 + 4 * g + r][kq * 16 + c] = f2bf(p);
    }

    // ---- PV(i): P A-frags from buf[pbR], V from registers
    bf16x8 pa0 = *reinterpret_cast<const bf16x8*>(&Plds[pbR][c][8 * g]);
    bf16x8 pa1 = *reinterpret_cast<const bf16x8*>(&Plds[pbR][16 + c][8 * g]);
    bf16x8 pa2 = *reinterpret_cast<const bf16x8*>(&Plds[pbR][32 + c][8 * g]);
    bf16x8 pa3 = *reinterpret_cast<const bf16x8*>(&Plds[pbR][48 + c][8 * g]);
    __builtin_amdgcn_s_setprio(1);
#pragma unroll
    for (int dt = 0; dt < 4; ++dt) {
      o[0][dt] = MFMA32(pa0, vR[dt], o[0][dt]);
      o[1][dt] = MFMA32(pa1, vR[dt], o[1][dt]);
      o[2][dt] = MFMA32(pa2, vR[dt], o[2][dt]);
      o[3][dt] = MFMA32(pa3, vR[dt], o[3][dt]);
    }
    __builtin_amdgcn_s_setprio(0);

    // ---- lgkm-only barrier: P writes/reads ordered; vmem stays in flight
    BARRIER_LGKM();
  };

#pragma unroll 1
  for (int i = 0; i < 60; i += 4) {
    body(kbuf[1], kbuf[3], vbuf[0], vbuf[3], i);
    body(kbuf[2], kbuf[0], vbuf[1], vbuf[0], i + 1);
    body(kbuf[3], kbuf[1], vbuf[2], vbuf[1], i + 2);
    body(kbuf[0], kbuf[2], vbuf[3], vbuf[2], i + 3);
  }
  body(kbuf[1], kbuf[3], vbuf[0], vbuf[3], 60);
  body(kbuf[2], kbuf[0], vbuf[1], vbuf[0], 61);
  body(kbuf[3], kbuf[1], vbuf[2], vbuf[1], 62);

  // ---- epilogue: PV(63) (P in buf1, V in vbuf[3])
  {
    bf16x8 pa0 = *reinterpret_cast<const bf16x8*>(&Plds[1][c][8 * g]);
    bf16x8 pa1 = *reinterpret_cast<const bf16x8*>(&Plds[1][16 + c][8 * g]);
    bf16x8 pa2 = *reinterpret_cast<const bf16x8*>(&Plds[1][32 + c][8 * g]);
    bf16x8 pa3 = *reinterpret_cast<const bf16x8*>(&Plds[1][48 + c][8 * g]);
#pragma unroll
    for (int dt = 0; dt < 4; ++dt) {
      o[0][dt] = MFMA32(pa0, vbuf[3][dt], o[0][dt]);
      o[1][dt] = MFMA32(pa1, vbuf[3][dt], o[1][dt]);
      o[2][dt] = MFMA32(pa2, vbuf[3][dt], o[2][dt]);
      o[3][dt] = MFMA32(pa3, vbuf[3][dt], o[3][dt]);
    }
  }

  // ---- denominator: reduce lp over 16 c-lanes, combine the 2 kq halves
#pragma unroll
  for (int r = 0; r < 4; ++r) {
    float v = lp[r];
    v += __shfl_xor(v, 1); v += __shfl_xor(v, 2);
    v += __shfl_xor(v, 4); v += __shfl_xor(v, 8);
    lp[r] = v;
  }
  if (c == 0) {
#pragma unroll
    for (int r = 0; r < 4; ++r) Lp[kq][qh * 16 + 4 * g + r] = lp[r];
  }
  __syncthreads();

  float* outb = out + ((size_t)b * N_ + q0) * D_;
#pragma unroll
  for (int qf2 = 0; qf2 < 4; ++qf2)
#pragma unroll
    for (int r = 0; r < 4; ++r) {
      int ql = qf2 * 16 + 4 * g + r;
      float L = Lp[0][ql] + Lp[1][ql];
      float inv = 1.0f / L;
#pragma unroll
      for (int df = 0; df < 4; ++df)
        outb[(size_t)ql * D_ + w * 64 + df * 16 + c] = o[qf2][df][r] * inv;
    }
}

// ---------------------------------------------------------------------------
extern "C" void kernel_launch(void* const* d_in, const int* in_sizes, int n_in,
                              void* d_out, int out_size, void* d_ws, size_t ws_size,
                              hipStream_t stream) {
  const float* X  = (const float*)d_in[0];
  const float* h  = (const float*)d_in[1];
  const float* WQ = (const float*)d_in[2];
  const float* bQ = (const float*)d_in[3];
  const float* WK = (const float*)d_in[4];
  const float* bK = (const float*)d_in[5];
  float* out = (float*)d_out;

  u16* Vf = (u16*)d_ws;                                // 16 MB
  u16* Qf = Vf + (size_t)B_ * D_ * N_;                 // 2 MB
  u16* Kf = Qf + (size_t)B_ * N_ * DK_;                // 2 MB

  prep_kernel<<<dim3(256), dim3(256), 0, stream>>>(h, X, WQ, bQ, WK, bK, Qf, Kf, Vf);
  attn_kernel<<<dim3(256), dim3(512), 0, stream>>>(Qf, Kf, Vf, out);
}

// Round 19
// 73.433 us; speedup vs baseline: 1.5976x; 1.0483x over previous
//
#include <hip/hip_runtime.h>
#include <hip/hip_bf16.h>

#define B_ 8
#define N_ 2048
#define D_ 512
#define DK_ 64

typedef float f32x4 __attribute__((ext_vector_type(4)));
typedef short bf16x8 __attribute__((ext_vector_type(8)));
typedef unsigned short u16;

__device__ __forceinline__ u16 f2bf(float f) {
  union { float f; unsigned u; } v; v.f = f;
  unsigned r = v.u + 0x7FFFu + ((v.u >> 16) & 1u);  // RNE, inputs finite
  return (u16)(r >> 16);
}

#define MFMA32(a, b, cacc) __builtin_amdgcn_mfma_f32_16x16x32_bf16((a), (b), (cacc), 0, 0, 0)

// lgkm-only barrier (validated R4/R10/R17/R18 incl. graph-replay reval)
#define BARRIER_LGKM() do {                                   \
    asm volatile("s_waitcnt lgkmcnt(0)" ::: "memory");        \
    __builtin_amdgcn_s_barrier();                             \
    asm volatile("" ::: "memory");                            \
  } while (0)

// ===========================================================================
// Fragment layouts (every attn global load = 64 lanes x 16B contiguous 1KB):
//  Qf/Kf: elem((b*128 + slab)*2 + ks)*512 + lane*8 + i
//         holds  M[slab*16 + (lane&15)][ks*32 + (lane>>4)*8 + i]
//  Vf:    elem(((b*32 + dt)*32 + nt)*2 + ks)*512 + lane*8 + i
//         holds  X[nt*64 + ks*32 + (lane>>4)*8 + i][dt*16 + (lane&15)]
// ===========================================================================

// ---------------------------------------------------------------------------
// prep (validated R18, byte-identical): fused vt+proj, one pass over X.
// ---------------------------------------------------------------------------
__global__ __launch_bounds__(256) void prep_kernel(
    const float* __restrict__ h, const float* __restrict__ X,
    const float* __restrict__ WQ, const float* __restrict__ bQ,
    const float* __restrict__ WK, const float* __restrict__ bK,
    u16* __restrict__ Qf, u16* __restrict__ Kf, u16* __restrict__ Vf) {
  int bid = blockIdx.x;
  int b = bid & 7, nt = bid >> 3;
  int n0 = nt * 64;
  int t = threadIdx.x, w = t >> 6, l = t & 63, g = l >> 4, c = l & 15;

  __shared__ u16 Xb16[64][520];

  int arow = n0 + w * 16 + c;
  const float* hrow = h + ((size_t)b * N_ + arow) * D_;
  const float* Xrow = X + ((size_t)b * N_ + arow) * D_;
  f32x4 accq[4], acck[4];
#pragma unroll
  for (int cf = 0; cf < 4; ++cf) {
    accq[cf] = (f32x4){0.f, 0.f, 0.f, 0.f};
    acck[cf] = (f32x4){0.f, 0.f, 0.f, 0.f};
  }
  for (int k0 = 0; k0 < D_; k0 += 32) {
    bf16x8 ah, ax;
    {
      f32x4 h0 = *reinterpret_cast<const f32x4*>(hrow + k0 + 8 * g);
      f32x4 h1 = *reinterpret_cast<const f32x4*>(hrow + k0 + 8 * g + 4);
      f32x4 x0 = *reinterpret_cast<const f32x4*>(Xrow + k0 + 8 * g);
      f32x4 x1 = *reinterpret_cast<const f32x4*>(Xrow + k0 + 8 * g + 4);
#pragma unroll
      for (int i = 0; i < 4; ++i) {
        ah[i] = (short)f2bf(h0[i]); ah[i + 4] = (short)f2bf(h1[i]);
        ax[i] = (short)f2bf(x0[i]); ax[i + 4] = (short)f2bf(x1[i]);
      }
    }
    *reinterpret_cast<bf16x8*>(&Xb16[w * 16 + c][k0 + 8 * g]) = ax;
#pragma unroll
    for (int cf = 0; cf < 4; ++cf) {
      bf16x8 bq, bk;
#pragma unroll
      for (int i = 0; i < 8; ++i) {
        int kk = k0 + 8 * g + i;
        bq[i] = (short)f2bf(WQ[(size_t)kk * DK_ + cf * 16 + c]);
        bk[i] = (short)f2bf(WK[(size_t)kk * DK_ + cf * 16 + c]);
      }
      accq[cf] = MFMA32(ah, bq, accq[cf]);
      acck[cf] = MFMA32(ax, bk, acck[cf]);
    }
  }
#pragma unroll
  for (int cf = 0; cf < 4; ++cf) {
    float vq = bQ[cf * 16 + c], vk = bK[cf * 16 + c];
    int ks = cf >> 1;
    int g2 = ((cf & 1) * 16 + c) >> 3;
    int i2 = c & 7;
#pragma unroll
    for (int r = 0; r < 4; ++r) {
      size_t e = ((size_t)(b * 128 + nt * 4 + w) * 2 + ks) * 512 +
                 (g2 * 16 + 4 * g + r) * 8 + i2;
      Qf[e] = f2bf((accq[cf][r] + vq) * 0.125f);
      Kf[e] = f2bf(acck[cf][r] + vk);
    }
  }

  __syncthreads();

#pragma unroll
  for (int dtl = 0; dtl < 8; ++dtl) {
    int dt = w * 8 + dtl;
#pragma unroll
    for (int ks = 0; ks < 2; ++ks) {
      bf16x8 v;
#pragma unroll
      for (int i = 0; i < 8; ++i) v[i] = Xb16[ks * 32 + 8 * g + i][dt * 16 + c];
      *reinterpret_cast<bf16x8*>(
          Vf + (((size_t)(b * 32 + dt) * 32 + nt) * 2 + ks) * 512 + l * 8) = v;
    }
  }
}

// ---------------------------------------------------------------------------
// attn: R10 structure with 4-deep P buffering and a barrier every TWO
// windows (64 -> 33 barriers). Between consecutive barriers, waves write
// P(2k+2),P(2k+3) (bufs (2k+2)&3,(2k+3)&3) and read P(2k),P(2k+1) (bufs
// (2k)&3,(2k+1)&3) -- disjoint sets; every cross-wave write->read pair is
// separated by >= 1 barrier. K 4-slot / V 4-slot register rotation by pair.
// ---------------------------------------------------------------------------
__global__ __launch_bounds__(512, 1) void attn_kernel(
    const u16* __restrict__ Qf, const u16* __restrict__ Kf,
    const u16* __restrict__ Vf, float* __restrict__ out) {
  int bid = blockIdx.x;
  int b = bid & 7, qt = bid >> 3;
  int q0 = qt * 64;
  int t = threadIdx.x, w = t >> 6, l = t & 63, g = l >> 4, c = l & 15;
  int qh = w >> 1, kq = w & 1;

  __shared__ u16 Plds[4][64][40];   // P 4-buffer [q 64][kv 32], stride 40 u16
  __shared__ float Lp[2][64];

  bf16x8 aq[2];
#pragma unroll
  for (int ks = 0; ks < 2; ++ks)
    aq[ks] = *reinterpret_cast<const bf16x8*>(
        Qf + ((size_t)(b * 128 + qt * 4 + qh) * 2 + ks) * 512 + l * 8);

  f32x4 o[4][4];
#pragma unroll
  for (int a = 0; a < 4; ++a)
#pragma unroll
    for (int d = 0; d < 4; ++d) o[a][d] = (f32x4){0.f, 0.f, 0.f, 0.f};
  float lp[4] = {0.f, 0.f, 0.f, 0.f};

  const u16* Kbase = Kf + ((size_t)(b * 256 + 2 * kq)) * 512 + l * 8;
  const u16* Vbase = Vf + ((size_t)(b * 32 + w * 4) * 64) * 512 + l * 8;

  bf16x8 kbuf[4][2], vbuf[4][4];

  // ---- prologue: K(0..3)/V(0..3); S(0)->P0, S(1)->P1; barrier
#pragma unroll
  for (int j = 0; j < 4; ++j) {
#pragma unroll
    for (int ks = 0; ks < 2; ++ks)
      kbuf[j][ks] = *reinterpret_cast<const bf16x8*>(
          Kbase + (size_t)(4 * j + ks) * 512);
#pragma unroll
    for (int f = 0; f < 4; ++f)
      vbuf[j][f] = *reinterpret_cast<const bf16x8*>(
          Vbase + (size_t)(f * 64 + j) * 512);
  }
#pragma unroll
  for (int j0 = 0; j0 < 2; ++j0) {
    f32x4 s = (f32x4){0.f, 0.f, 0.f, 0.f};
    s = MFMA32(aq[0], kbuf[j0][0], s);
    s = MFMA32(aq[1], kbuf[j0][1], s);
#pragma unroll
    for (int r = 0; r < 4; ++r) {
      float p = __expf(s[r]); lp[r] += p;
      Plds[j0][qh * 16 + 4 * g + r][kq * 16 + c] = f2bf(p);
    }
  }
  BARRIER_LGKM();

  // pair body: windows (k2, k2+1). S(k2+2),S(k2+3) from kS0/kS1; P writes
  // pW0/pW1; PV(k2),PV(k2+1) from Plds[pR0]/[pR1] + vR0/vR1; K loads
  // (k2+4),(k2+5) -> kL0/kL1; V loads (k2+4),(k2+5) -> vR0/vR1 (after PV).
  auto pair = [&](bf16x8 (&kS0)[2], bf16x8 (&kS1)[2],
                  bf16x8 (&kL0)[2], bf16x8 (&kL1)[2],
                  bf16x8 (&vR0)[4], bf16x8 (&vR1)[4],
                  int k2, int pW0, int pW1, int pR0, int pR1) {
    const int jA = (k2 + 4) & 63, jB = (k2 + 5) & 63;

    // K prefetch (consumed by S one pair out)
#pragma unroll
    for (int ks = 0; ks < 2; ++ks)
      kL0[ks] = *reinterpret_cast<const bf16x8*>(
          Kbase + (size_t)(4 * jA + ks) * 512);
#pragma unroll
    for (int ks = 0; ks < 2; ++ks)
      kL1[ks] = *reinterpret_cast<const bf16x8*>(
          Kbase + (size_t)(4 * jB + ks) * 512);

    // ---- S(k2+2) -> P[pW0]
    {
      f32x4 s = (f32x4){0.f, 0.f, 0.f, 0.f};
      s = MFMA32(aq[0], kS0[0], s);
      s = MFMA32(aq[1], kS0[1], s);
#pragma unroll
      for (int r = 0; r < 4; ++r) {
        float p = __expf(s[r]); lp[r] += p;
        Plds[pW0][qh * 16 + 4 * g + r][kq * 16 + c] = f2bf(p);
      }
    }
    // ---- S(k2+3) -> P[pW1]
    {
      f32x4 s = (f32x4){0.f, 0.f, 0.f, 0.f};
      s = MFMA32(aq[0], kS1[0], s);
      s = MFMA32(aq[1], kS1[1], s);
#pragma unroll
      for (int r = 0; r < 4; ++r) {
        float p = __expf(s[r]); lp[r] += p;
        Plds[pW1][qh * 16 + 4 * g + r][kq * 16 + c] = f2bf(p);
      }
    }

    // ---- PV(k2) from Plds[pR0] + vR0
    {
      bf16x8 pa0 = *reinterpret_cast<const bf16x8*>(&Plds[pR0][c][8 * g]);
      bf16x8 pa1 = *reinterpret_cast<const bf16x8*>(&Plds[pR0][16 + c][8 * g]);
      bf16x8 pa2 = *reinterpret_cast<const bf16x8*>(&Plds[pR0][32 + c][8 * g]);
      bf16x8 pa3 = *reinterpret_cast<const bf16x8*>(&Plds[pR0][48 + c][8 * g]);
      __builtin_amdgcn_s_setprio(1);
#pragma unroll
      for (int dt = 0; dt < 4; ++dt) {
        o[0][dt] = MFMA32(pa0, vR0[dt], o[0][dt]);
        o[1][dt] = MFMA32(pa1, vR0[dt], o[1][dt]);
        o[2][dt] = MFMA32(pa2, vR0[dt], o[2][dt]);
        o[3][dt] = MFMA32(pa3, vR0[dt], o[3][dt]);
      }
      __builtin_amdgcn_s_setprio(0);
    }
    // V(jA) into the just-consumed slot (in-wave WAR, compiler-ordered)
#pragma unroll
    for (int f = 0; f < 4; ++f)
      vR0[f] = *reinterpret_cast<const bf16x8*>(
          Vbase + (size_t)(f * 64 + jA) * 512);

    // ---- PV(k2+1) from Plds[pR1] + vR1
    {
      bf16x8 pa0 = *reinterpret_cast<const bf16x8*>(&Plds[pR1][c][8 * g]);
      bf16x8 pa1 = *reinterpret_cast<const bf16x8*>(&Plds[pR1][16 + c][8 * g]);
      bf16x8 pa2 = *reinterpret_cast<const bf16x8*>(&Plds[pR1][32 + c][8 * g]);
      bf16x8 pa3 = *reinterpret_cast<const bf16x8*>(&Plds[pR1][48 + c][8 * g]);
      __builtin_amdgcn_s_setprio(1);
#pragma unroll
      for (int dt = 0; dt < 4; ++dt) {
        o[0][dt] = MFMA32(pa0, vR1[dt], o[0][dt]);
        o[1][dt] = MFMA32(pa1, vR1[dt], o[1][dt]);
        o[2][dt] = MFMA32(pa2, vR1[dt], o[2][dt]);
        o[3][dt] = MFMA32(pa3, vR1[dt], o[3][dt]);
      }
      __builtin_amdgcn_s_setprio(0);
    }
#pragma unroll
    for (int f = 0; f < 4; ++f)
      vR1[f] = *reinterpret_cast<const bf16x8*>(
          Vbase + (size_t)(f * 64 + jB) * 512);

    BARRIER_LGKM();
  };

  // pairs: 2k = 0..58 in the loop, final even pair 2k = 60 after.
#pragma unroll 1
  for (int k2 = 0; k2 < 60; k2 += 4) {
    pair(kbuf[2], kbuf[3], kbuf[0], kbuf[1], vbuf[0], vbuf[1], k2,     2, 3, 0, 1);
    pair(kbuf[0], kbuf[1], kbuf[2], kbuf[3], vbuf[2], vbuf[3], k2 + 2, 0, 1, 2, 3);
  }
  pair(kbuf[2], kbuf[3], kbuf[0], kbuf[1], vbuf[0], vbuf[1], 60, 2, 3, 0, 1);

  // ---- epilogue: PV(62) from Plds[2]+vbuf[2], PV(63) from Plds[3]+vbuf[3]
#pragma unroll
  for (int e = 0; e < 2; ++e) {
    const int pb = 2 + e;
    bf16x8 pa0 = *reinterpret_cast<const bf16x8*>(&Plds[pb][c][8 * g]);
    bf16x8 pa1 = *reinterpret_cast<const bf16x8*>(&Plds[pb][16 + c][8 * g]);
    bf16x8 pa2 = *reinterpret_cast<const bf16x8*>(&Plds[pb][32 + c][8 * g]);
    bf16x8 pa3 = *reinterpret_cast<const bf16x8*>(&Plds[pb][48 + c][8 * g]);
#pragma unroll
    for (int dt = 0; dt < 4; ++dt) {
      o[0][dt] = MFMA32(pa0, vbuf[pb][dt], o[0][dt]);
      o[1][dt] = MFMA32(pa1, vbuf[pb][dt], o[1][dt]);
      o[2][dt] = MFMA32(pa2, vbuf[pb][dt], o[2][dt]);
      o[3][dt] = MFMA32(pa3, vbuf[pb][dt], o[3][dt]);
    }
  }

  // ---- denominator: reduce lp over 16 c-lanes, combine the 2 kq halves
#pragma unroll
  for (int r = 0; r < 4; ++r) {
    float v = lp[r];
    v += __shfl_xor(v, 1); v += __shfl_xor(v, 2);
    v += __shfl_xor(v, 4); v += __shfl_xor(v, 8);
    lp[r] = v;
  }
  if (c == 0) {
#pragma unroll
    for (int r = 0; r < 4; ++r) Lp[kq][qh * 16 + 4 * g + r] = lp[r];
  }
  __syncthreads();

  float* outb = out + ((size_t)b * N_ + q0) * D_;
#pragma unroll
  for (int qf2 = 0; qf2 < 4; ++qf2)
#pragma unroll
    for (int r = 0; r < 4; ++r) {
      int ql = qf2 * 16 + 4 * g + r;
      float L = Lp[0][ql] + Lp[1][ql];
      float inv = 1.0f / L;
#pragma unroll
      for (int df = 0; df < 4; ++df)
        outb[(size_t)ql * D_ + w * 64 + df * 16 + c] = o[qf2][df][r] * inv;
    }
}

// ---------------------------------------------------------------------------
extern "C" void kernel_launch(void* const* d_in, const int* in_sizes, int n_in,
                              void* d_out, int out_size, void* d_ws, size_t ws_size,
                              hipStream_t stream) {
  const float* X  = (const float*)d_in[0];
  const float* h  = (const float*)d_in[1];
  const float* WQ = (const float*)d_in[2];
  const float* bQ = (const float*)d_in[3];
  const float* WK = (const float*)d_in[4];
  const float* bK = (const float*)d_in[5];
  float* out = (float*)d_out;

  u16* Vf = (u16*)d_ws;                                // 16 MB
  u16* Qf = Vf + (size_t)B_ * D_ * N_;                 // 2 MB
  u16* Kf = Qf + (size_t)B_ * N_ * DK_;                // 2 MB

  prep_kernel<<<dim3(256), dim3(256), 0, stream>>>(h, X, WQ, bQ, WK, bK, Qf, Kf, Vf);
  attn_kernel<<<dim3(256), dim3(512), 0, stream>>>(Qf, Kf, Vf, out);
}